// Round 6
// baseline (639.541 us; speedup 1.0000x reference)
//
#include <hip/hip_runtime.h>

// ---------------------------------------------------------------------------
// metaLinear: y[t,o] = sum_j x2[t,j] * ( x1[t,:]@W[j*64+o,:] + bvec[j*64+o] )
//   T=16384, IN1=256, IN2=64 (j), OUT=64 (o).
// Round 6: wave = 64 tok x 64 o (x2 reuse on BOTH operands: A(W) from L1 at
// 64 B/cyc/CU, B(x1) from LDS at 64 B/cyc/CU, 4 independent MFMA chains).
// 512-thread WGs: 8 waves share one 64-token x1 tile and split j 8-way
// internally (8 j's per wave) -> barrier-free j-loop, grid 256 = 1 WG/CU =
// 2 waves/SIMD, no external reduce kernel. Epilogue: 4-phase LDS all-reduce
// to owner waves 0-3, bias via MFMA matmul (verified R5 pattern), store.
// ---------------------------------------------------------------------------

#define FRAG_SHORTS 512                  // 64 lanes * 8 bf16
#define JSTRIDE (2 * 16 * FRAG_SHORTS)   // 16384 shorts per j (2 oh, 16 ks)
#define SX_STRIDE 264                    // shorts per x1 row (528 B, 16B-mult)
#define BV_OFF (64 * SX_STRIDE)          // bvec bf16 region offset (shorts)

typedef __bf16 bf16x8 __attribute__((ext_vector_type(8)));
typedef float  f32x16 __attribute__((ext_vector_type(16)));

static __device__ __forceinline__ unsigned short f2bf(float f) {
  union { float f; unsigned u; } v; v.f = f;
  unsigned r = v.u + 0x7FFFu + ((v.u >> 16) & 1u);   // RNE
  return (unsigned short)(r >> 16);
}

// Wf[((j*2+ot)*16 + ks)*512 + lane*8 + e] =
//     bf16( W[row = 64j+32ot+(lane&31)][col = 16ks + 8*(lane>>5) + e] )
__global__ void prep_w(const float* __restrict__ W, unsigned short* __restrict__ Wf) {
  int wv   = threadIdx.x >> 6;
  int lane = threadIdx.x & 63;
  int l31  = lane & 31;
  int lg   = lane >> 5;
  int task = blockIdx.x * 4 + wv;       // 0..2047
  int ks   = task & 15;
  int joh  = task >> 4;                 // j*2+ot
  int r    = 32 * joh + l31;
  int col  = ks * 16 + lg * 8;

  const float4* src = (const float4*)(W + (size_t)r * 256 + col);
  float4 a = src[0], b = src[1];
  ushort4 u0, u1;
  u0.x = f2bf(a.x); u0.y = f2bf(a.y); u0.z = f2bf(a.z); u0.w = f2bf(a.w);
  u1.x = f2bf(b.x); u1.y = f2bf(b.y); u1.z = f2bf(b.z); u1.w = f2bf(b.w);
  size_t fb = ((size_t)joh * 16 + ks) * FRAG_SHORTS;
  *(ushort4*)&Wf[fb + lane * 8 + 0] = u0;
  *(ushort4*)&Wf[fb + lane * 8 + 4] = u1;
}

// Grid: 256 WGs x 512 threads (8 waves). WG g owns tokens [g*64, +64) and
// ALL 64 outputs. Wave wv handles j in [wv*8, wv*8+8). Tiles per wave:
// (tt,ot) in {0,1}^2; tile id = tt*2+ot; owner wave of tile i is wave i.
__global__ __launch_bounds__(512, 1)
void meta_main(const float* __restrict__ x1, const float* __restrict__ x2,
               const float* __restrict__ bvec,
               const unsigned short* __restrict__ Wf, float* __restrict__ out) {
  __shared__ unsigned short sX1[64 * SX_STRIDE + 4096];  // 33792 B x1 + 8 KB bvec

  const int tid  = threadIdx.x;
  const int lane = tid & 63;
  const int wv   = tid >> 6;            // 0..7
  const int l31  = lane & 31;
  const int lg   = lane >> 5;
  const long tok0 = (long)blockIdx.x * 64;

  // ---- stage x1 tile (64 tok x 256) fp32 -> bf16, row stride 264 ----
  {
    const float4* src = (const float4*)(x1 + tok0 * 256);
    #pragma unroll
    for (int it = 0; it < 8; ++it) {
      int fi4 = it * 512 + tid;         // 4096 float4 = 64 rows x 64
      float4 v = src[fi4];
      int row = fi4 >> 6;
      int col = (fi4 & 63) * 4;
      ushort4 b;
      b.x = f2bf(v.x); b.y = f2bf(v.y); b.z = f2bf(v.z); b.w = f2bf(v.w);
      *(ushort4*)&sX1[row * SX_STRIDE + col] = b;
    }
    // bvec fp32 -> bf16 into its own region (read only in epilogue)
    #pragma unroll
    for (int c = 0; c < 2; ++c) {
      int i = c * 512 + tid;            // 1024 float4
      float4 v = ((const float4*)bvec)[i];
      ushort4 u;
      u.x = f2bf(v.x); u.y = f2bf(v.y); u.z = f2bf(v.z); u.w = f2bf(v.w);
      *(ushort4*)&sX1[BV_OFF + i * 4] = u;
    }
  }
  __syncthreads();

  // ---- barrier-free j-loop: 8 j's per wave, 64 MFMA per j, 4 chains ----
  const int j0 = wv * 8;
  const float* x2r0 = x2 + (tok0 + l31) * 64;        // token tile 0 row
  const float* x2r1 = x2 + (tok0 + 32 + l31) * 64;   // token tile 1 row

  f32x16 yacc[4];
  #pragma unroll
  for (int t = 0; t < 4; ++t)
    #pragma unroll
    for (int r = 0; r < 16; ++r) yacc[t][r] = 0.0f;

  const unsigned short* ap = Wf + lane * 8;
  const unsigned short* b0 = &sX1[l31 * SX_STRIDE + lg * 8];
  const unsigned short* b1 = &sX1[(32 + l31) * SX_STRIDE + lg * 8];

  for (int g = 0; g < 2; ++g) {
    float4 qa = *(const float4*)(x2r0 + j0 + 4 * g);
    float4 qb = *(const float4*)(x2r1 + j0 + 4 * g);
    #pragma unroll
    for (int u = 0; u < 4; ++u) {
      const int j = j0 + 4 * g + u;
      const float x2s0 = (u == 0) ? qa.x : (u == 1) ? qa.y : (u == 2) ? qa.z : qa.w;
      const float x2s1 = (u == 0) ? qb.x : (u == 1) ? qb.y : (u == 2) ? qb.z : qb.w;
      const size_t jb_ = (size_t)j * JSTRIDE;

      f32x16 w00, w01, w10, w11;
      #pragma unroll
      for (int r = 0; r < 16; ++r) { w00[r] = 0.0f; w01[r] = 0.0f; w10[r] = 0.0f; w11[r] = 0.0f; }

      #pragma unroll
      for (int q = 0; q < 4; ++q) {
        bf16x8 A0[4], A1[4], B0[4], B1[4];
        #pragma unroll
        for (int kk = 0; kk < 4; ++kk) {
          int ks = 4 * q + kk;
          A0[kk] = *(const bf16x8*)(ap + jb_ + (size_t)ks * 512);          // ot=0
          A1[kk] = *(const bf16x8*)(ap + jb_ + 8192 + (size_t)ks * 512);   // ot=1
          B0[kk] = *(const bf16x8*)(b0 + ks * 16);                         // tt=0
          B1[kk] = *(const bf16x8*)(b1 + ks * 16);                         // tt=1
        }
        #pragma unroll
        for (int kk = 0; kk < 4; ++kk) {   // 4 independent chains, stride 4
          w00 = __builtin_amdgcn_mfma_f32_32x32x16_bf16(A0[kk], B0[kk], w00, 0, 0, 0);
          w01 = __builtin_amdgcn_mfma_f32_32x32x16_bf16(A1[kk], B0[kk], w01, 0, 0, 0);
          w10 = __builtin_amdgcn_mfma_f32_32x32x16_bf16(A0[kk], B1[kk], w10, 0, 0, 0);
          w11 = __builtin_amdgcn_mfma_f32_32x32x16_bf16(A1[kk], B1[kk], w11, 0, 0, 0);
        }
      }
      #pragma unroll
      for (int r = 0; r < 16; ++r) {
        yacc[0][r] += x2s0 * w00[r];     // (tt0,ot0)
        yacc[1][r] += x2s0 * w01[r];     // (tt0,ot1)
        yacc[2][r] += x2s1 * w10[r];     // (tt1,ot0)
        yacc[3][r] += x2s1 * w11[r];     // (tt1,ot1)
      }
    }
  }

  // ---- epilogue: 4-phase LDS all-reduce (8 waves -> owner waves 0..3) ----
  float* R = (float*)sX1;               // 32 KB region (bvec region disjoint)
  #pragma unroll
  for (int t = 0; t < 4; ++t) {
    __syncthreads();                    // region free / prior phase done
    #pragma unroll
    for (int q4 = 0; q4 < 4; ++q4) {
      float4 v;
      v.x = yacc[t][4 * q4 + 0]; v.y = yacc[t][4 * q4 + 1];
      v.z = yacc[t][4 * q4 + 2]; v.w = yacc[t][4 * q4 + 3];
      *(float4*)&R[wv * 1024 + lane * 16 + q4 * 4] = v;
    }
    __syncthreads();
    if (wv == t) {
      #pragma unroll
      for (int s = 0; s < 8; ++s) {
        if (s == t) continue;
        #pragma unroll
        for (int q4 = 0; q4 < 4; ++q4) {
          float4 v = *(const float4*)&R[s * 1024 + lane * 16 + q4 * 4];
          yacc[t][4 * q4 + 0] += v.x; yacc[t][4 * q4 + 1] += v.y;
          yacc[t][4 * q4 + 2] += v.z; yacc[t][4 * q4 + 3] += v.w;
        }
      }
    }
  }

  // ---- owner waves: bias matmul (y += x2 @ Bmat) + store ----
  if (wv < 4) {
    const int tt = wv >> 1, ot = wv & 1;
    const __bf16* bb = (const __bf16*)(sX1 + BV_OFF);
    f32x16 acc = yacc[wv];
    #pragma unroll
    for (int k = 0; k < 4; ++k) {
      bf16x8 Af, Bf;
      #pragma unroll
      for (int e = 0; e < 8; ++e)       // A[m=o][k'=j'] = bvec[j'*64+o]
        Af[e] = bb[(16 * k + 8 * lg + e) * 64 + 32 * ot + l31];
      const float* xr = x2 + (tok0 + tt * 32 + l31) * 64 + 16 * k + 8 * lg;
      float4 p0 = *(const float4*)xr;
      float4 p1 = *(const float4*)(xr + 4);
      Bf[0] = (__bf16)p0.x; Bf[1] = (__bf16)p0.y; Bf[2] = (__bf16)p0.z; Bf[3] = (__bf16)p0.w;
      Bf[4] = (__bf16)p1.x; Bf[5] = (__bf16)p1.y; Bf[6] = (__bf16)p1.z; Bf[7] = (__bf16)p1.w;
      acc = __builtin_amdgcn_mfma_f32_32x32x16_bf16(Af, Bf, acc, 0, 0, 0);
    }
    // D row o_local = (r&3)+8*(r>>2)+4*lg, col = token = l31
    float* yout = out + (tok0 + tt * 32 + l31) * 64 + ot * 32;
    #pragma unroll
    for (int q4 = 0; q4 < 4; ++q4) {
      float4 v;
      v.x = acc[4 * q4 + 0]; v.y = acc[4 * q4 + 1];
      v.z = acc[4 * q4 + 2]; v.w = acc[4 * q4 + 3];
      *(float4*)&yout[q4 * 8 + 4 * lg] = v;
    }
  }
}

extern "C" void kernel_launch(void* const* d_in, const int* in_sizes, int n_in,
                              void* d_out, int out_size, void* d_ws, size_t ws_size,
                              hipStream_t stream) {
  const float* x1 = (const float*)d_in[0];   // (4,4096,256) f32
  const float* x2 = (const float*)d_in[1];   // (4,4096,64)  f32
  const float* W  = (const float*)d_in[2];   // (4096,256)   f32
  const float* bv = (const float*)d_in[3];   // (4096,)      f32
  float* y = (float*)d_out;                  // (4,4096,64)  f32
  unsigned short* Wf = (unsigned short*)d_ws;  // 64*16384*2 = 2,097,152 B

  prep_w<<<512, 256, 0, stream>>>(W, Wf);
  meta_main<<<256, 512, 0, stream>>>(x1, x2, bv, Wf, y);
}